// Round 9
// baseline (175.902 us; speedup 1.0000x reference)
//
#include <hip/hip_runtime.h>
#include <math.h>

using u16 = unsigned short;
using u32 = unsigned int;

namespace {
constexpr int Hdim = 128;
constexpr int Pn = 50000;
constexpr int Cn = 20000;
constexpr int Bn = 4;
constexpr int NClause = Bn * Cn;   // 80000
constexpr int NRows = Bn * Pn;     // 200000
constexpr int CAP = 64;            // max clauses per variable (mean deg 4.8; P(>=64) ~ e^-150)
}

typedef __attribute__((ext_vector_type(4))) float f32x4;
typedef __attribute__((ext_vector_type(8))) short bf16x8;

static __device__ __forceinline__ float bf2f(u16 v) {
    u32 u = ((u32)v) << 16;
    return __builtin_bit_cast(float, u);
}
static __device__ __forceinline__ u16 f2bf(float f) {
    u32 u = __builtin_bit_cast(u32, f);
    u32 r = u + 0x7FFFu + ((u >> 16) & 1u);
    return (u16)(r >> 16);
}

// ONE setup kernel: redundant per-row weight-chain (no inter-stage sync), packs
// Wcomb & W_s1 into MFMA B-frag layout, folds bias, zeros cursor.
__global__ __launch_bounds__(128) void setup_kernel(
    const float* __restrict__ W_vc, const float* __restrict__ b_vc,
    const float* __restrict__ W_ce, const float* __restrict__ b_ce,
    const float* __restrict__ W_cv, const float* __restrict__ b_cv,
    const float* __restrict__ W_s1,
    u16* __restrict__ WcombPack, u16* __restrict__ Ws1Pack,
    float* __restrict__ bias_comb, int* __restrict__ cursor) {
    int o = blockIdx.x, t = threadIdx.x;
    __shared__ float u[Hdim];
    __shared__ float red[Hdim];
    float acc = 0.f;
#pragma unroll 8
    for (int h = 0; h < Hdim; ++h) acc = fmaf(W_cv[o * Hdim + h], W_ce[h * Hdim + t], acc);
    u[t] = acc;
    float b1 = b_ce[t];
#pragma unroll 8
    for (int h = 0; h < Hdim; ++h) b1 = fmaf(W_ce[t * Hdim + h], b_vc[h], b1);
    red[t] = W_cv[o * Hdim + t] * b1;
    __syncthreads();
#pragma unroll
    for (int s = 64; s > 0; s >>= 1) {
        if (t < s) red[t] += red[t + s];
        __syncthreads();
    }
    if (t == 0) bias_comb[o] = red[0] + b_cv[o];
    float w = 0.f;
#pragma unroll 8
    for (int h = 0; h < Hdim; ++h) w = fmaf(u[h], W_vc[h * Hdim + t], w);
    // pack element (n=o, k=t): dst[((nt*4+ks)*64 + lane)*8 + j], lane = lofs*16 + (n&15)
    int nt = o >> 4, ks = t >> 5, lofs = (t >> 3) & 3, j = t & 7;
    int lane = lofs * 16 + (o & 15);
    size_t dst = (size_t)(((nt * 4 + ks) * 64 + lane)) * 8 + j;
    WcombPack[dst] = f2bf(w);
    Ws1Pack[dst] = f2bf(W_s1[o * Hdim + t]);
    for (int i = o * 128 + t; i < Pn; i += 128 * 128) cursor[i] = 0;
}

// bucketed CSR: entries[p*CAP + pos] = fid, cursor[p] = degree (first-occurrence dedup)
__global__ void fill_kernel(const int* __restrict__ ci, int* __restrict__ cursor,
                            int* __restrict__ entries) {
    int fid = blockIdx.x * blockDim.x + threadIdx.x;
    if (fid >= NClause) return;
    int i0 = ci[fid * 3 + 0], i1 = ci[fid * 3 + 1], i2 = ci[fid * 3 + 2];
    int pos = atomicAdd(&cursor[i0], 1);
    entries[i0 * CAP + pos] = fid;
    if (i1 != i0) { pos = atomicAdd(&cursor[i1], 1); entries[i1 * CAP + pos] = fid; }
    if (i2 != i0 && i2 != i1) { pos = atomicAdd(&cursor[i2], 1); entries[i2 * CAP + pos] = fid; }
}

// Fused gather + mean + GEMM per clause, A-frags gathered DIRECTLY per lane
// (no input LDS staging): M[fid] = bf16( W * mean3(rows) + (FROM_F32 ? bias : 0) )
template <int FROM_F32>
__global__ __launch_bounds__(512) void clause_kernel(
    const int* __restrict__ ci, const float* __restrict__ vs0, const u16* __restrict__ msgs,
    const u16* __restrict__ Bpack, const float* __restrict__ bias, u16* __restrict__ M) {
    __shared__ __align__(16) u16 Btile[128 * 128];   // 32 KB
    __shared__ __align__(16) u16 Otile[128 * 136];   // 34 KB output staging
    int tid = threadIdx.x;
    int block0 = blockIdx.x * 128;
    {   // stage packed B
        const bf16x8* s = (const bf16x8*)Bpack;
        bf16x8* d = (bf16x8*)Btile;
#pragma unroll
        for (int i = 0; i < 4; ++i) d[tid + i * 512] = s[tid + i * 512];
    }
    __syncthreads();
    int w = tid >> 6, l = tid & 63;
    int fid = block0 + w * 16 + (l & 15);
    int kofs = (l >> 4) * 8;
    int i0 = ci[fid * 3 + 0], i1 = ci[fid * 3 + 1], i2 = ci[fid * 3 + 2];
    f32x4 acc[8];
#pragma unroll
    for (int nt = 0; nt < 8; ++nt) acc[nt] = (f32x4){0.f, 0.f, 0.f, 0.f};
    const float* fb = FROM_F32 ? vs0 + (size_t)(fid / Cn) * Pn * Hdim : nullptr;
#pragma unroll
    for (int ks = 0; ks < 4; ++ks) {
        int co = ks * 32 + kofs;
        float s[8];
        if (FROM_F32) {
            const float* r0 = fb + (size_t)i0 * Hdim + co;
            const float* r1 = fb + (size_t)i1 * Hdim + co;
            const float* r2 = fb + (size_t)i2 * Hdim + co;
            f32x4 a0 = *(const f32x4*)r0, a1 = *(const f32x4*)(r0 + 4);
            f32x4 b0 = *(const f32x4*)r1, b1 = *(const f32x4*)(r1 + 4);
            f32x4 c0 = *(const f32x4*)r2, c1 = *(const f32x4*)(r2 + 4);
#pragma unroll
            for (int j = 0; j < 4; ++j) {
                s[j] = a0[j] + b0[j] + c0[j];
                s[j + 4] = a1[j] + b1[j] + c1[j];
            }
        } else {
            bf16x8 v0 = *(const bf16x8*)(msgs + (size_t)i0 * Hdim + co);
            bf16x8 v1 = *(const bf16x8*)(msgs + (size_t)i1 * Hdim + co);
            bf16x8 v2 = *(const bf16x8*)(msgs + (size_t)i2 * Hdim + co);
#pragma unroll
            for (int j = 0; j < 8; ++j)
                s[j] = bf2f((u16)v0[j]) + bf2f((u16)v1[j]) + bf2f((u16)v2[j]);
        }
        bf16x8 af;
#pragma unroll
        for (int j = 0; j < 8; ++j) af[j] = (short)f2bf(s[j] * (1.f / 3.f));
#pragma unroll
        for (int nt = 0; nt < 8; ++nt) {
            bf16x8 bfr = *(const bf16x8*)(&Btile[((nt * 4 + ks) * 64 + l) * 8]);
            acc[nt] = __builtin_amdgcn_mfma_f32_16x16x32_bf16(af, bfr, acc[nt], 0, 0, 0);
        }
    }
    int crow = w * 16 + (l >> 4) * 4;
#pragma unroll
    for (int nt = 0; nt < 8; ++nt) {
        int col = nt * 16 + (l & 15);
        float bc = FROM_F32 ? bias[col] : 0.f;   // iter2: bias algebraically absorbed
#pragma unroll
        for (int reg = 0; reg < 4; ++reg)
            Otile[(crow + reg) * 136 + col] = f2bf(acc[nt][reg] + bc);
    }
    __syncthreads();
#pragma unroll
    for (int pass = 0; pass < 4; ++pass) {
        int t = pass * 512 + tid;
        int r = t >> 4, seg = t & 15;
        *(bf16x8*)(M + (size_t)(block0 + r) * Hdim + seg * 8) =
            *(const bf16x8*)(&Otile[r * 136 + seg * 8]);
    }
}

// iter1: msgs[p] = deg>0 ? (1/deg) sum M[fid] : 0          (= mask(W*V1 + b))
// iter2: msgs[p] = 2*msgs[p] + (deg>0 ? (1/deg) sum M[fid] : 0)
__global__ __launch_bounds__(256) void var_kernel(const u16* __restrict__ M,
                                                  const int* __restrict__ counts,
                                                  const int* __restrict__ entries,
                                                  u16* __restrict__ msgs, int iter2) {
    int wave = threadIdx.x >> 6, lane = threadIdx.x & 63;
    int p = blockIdx.x * 4 + wave;
    if (p >= Pn) return;
    int deg = counts[p];
    const int* ep = entries + p * CAP;
    float a0 = 0.f, a1 = 0.f;
    for (int e = 0; e < deg; ++e) {
        int cid = ep[e];
        u32 v = *(const u32*)(M + (size_t)cid * Hdim + lane * 2);
        a0 += bf2f((u16)(v & 0xffffu));
        a1 += bf2f((u16)(v >> 16));
    }
    if (deg > 0) { float inv = 1.f / (float)deg; a0 *= inv; a1 *= inv; }
    u32* mp = (u32*)(msgs + (size_t)p * Hdim + lane * 2);
    if (iter2) {
        u32 old = *mp;
        a0 += 2.f * bf2f((u16)(old & 0xffffu));
        a1 += 2.f * bf2f((u16)(old >> 16));
    }
    *mp = (u32)f2bf(a0) | ((u32)f2bf(a1) << 16);
}

// out[row] = sigmoid( W_s2 . relu( (vs0[row]+msgs[row%Pn]) * W_s1^T + b_s1 ) + b_s2 )
// No input LDS staging: per-lane direct A-frag gather. LDS = Btile only -> full occupancy.
__global__ __launch_bounds__(512) void final_kernel(
    const float* __restrict__ vs0, const u16* __restrict__ msgs, const u16* __restrict__ Bpack,
    const float* __restrict__ b_s1, const float* __restrict__ W_s2, const float* __restrict__ b_s2,
    float* __restrict__ out) {
    __shared__ __align__(16) u16 Btile[128 * 128];   // 32 KB only
    int tid = threadIdx.x;
    int block0 = blockIdx.x * 128;
    {
        const bf16x8* s = (const bf16x8*)Bpack;
        bf16x8* d = (bf16x8*)Btile;
#pragma unroll
        for (int i = 0; i < 4; ++i) d[tid + i * 512] = s[tid + i * 512];
    }
    __syncthreads();
    int w = tid >> 6, l = tid & 63;
    int row = block0 + w * 16 + (l & 15);
    int rowc = row < NRows ? row : NRows - 1;
    int p = rowc % Pn;
    int kofs = (l >> 4) * 8;
    const float* vrow = vs0 + (size_t)rowc * Hdim;
    const u16* mrow = msgs + (size_t)p * Hdim;
    f32x4 acc[8];
#pragma unroll
    for (int nt = 0; nt < 8; ++nt) acc[nt] = (f32x4){0.f, 0.f, 0.f, 0.f};
#pragma unroll
    for (int ks = 0; ks < 4; ++ks) {
        int co = ks * 32 + kofs;
        f32x4 x = *(const f32x4*)(vrow + co), y = *(const f32x4*)(vrow + co + 4);
        bf16x8 m = *(const bf16x8*)(mrow + co);
        bf16x8 af;
#pragma unroll
        for (int j = 0; j < 4; ++j) {
            af[j] = (short)f2bf(x[j] + bf2f((u16)m[j]));
            af[j + 4] = (short)f2bf(y[j] + bf2f((u16)m[j + 4]));
        }
#pragma unroll
        for (int nt = 0; nt < 8; ++nt) {
            bf16x8 bfr = *(const bf16x8*)(&Btile[((nt * 4 + ks) * 64 + l) * 8]);
            acc[nt] = __builtin_amdgcn_mfma_f32_16x16x32_bf16(af, bfr, acc[nt], 0, 0, 0);
        }
    }
    float part[4] = {0.f, 0.f, 0.f, 0.f};
#pragma unroll
    for (int nt = 0; nt < 8; ++nt) {
        int col = nt * 16 + (l & 15);
        float b1 = b_s1[col], w2 = W_s2[col];
#pragma unroll
        for (int reg = 0; reg < 4; ++reg)
            part[reg] += fmaxf(acc[nt][reg] + b1, 0.f) * w2;
    }
#pragma unroll
    for (int m = 1; m < 16; m <<= 1)
#pragma unroll
        for (int reg = 0; reg < 4; ++reg) part[reg] += __shfl_xor(part[reg], m, 64);
    if ((l & 15) == 0) {
        float lb = b_s2[0];
        int row0 = block0 + w * 16 + (l >> 4) * 4;
#pragma unroll
        for (int reg = 0; reg < 4; ++reg)
            if (row0 + reg < NRows)
                out[row0 + reg] = 1.f / (1.f + expf(-(part[reg] + lb)));
    }
}

extern "C" void kernel_launch(void* const* d_in, const int* in_sizes, int n_in,
                              void* d_out, int out_size, void* d_ws, size_t ws_size,
                              hipStream_t stream) {
    (void)in_sizes; (void)n_in; (void)out_size; (void)ws_size;
    const int* ci = (const int*)d_in[0];
    const float* vs0 = (const float*)d_in[1];
    const float* W_vc = (const float*)d_in[2];
    const float* b_vc = (const float*)d_in[3];
    const float* W_ce = (const float*)d_in[4];
    const float* b_ce = (const float*)d_in[5];
    const float* W_cv = (const float*)d_in[6];
    const float* b_cv = (const float*)d_in[7];
    const float* W_s1 = (const float*)d_in[8];
    const float* b_s1 = (const float*)d_in[9];
    const float* W_s2 = (const float*)d_in[10];
    const float* b_s2 = (const float*)d_in[11];
    float* out = (float*)d_out;

    char* ws = (char*)d_ws;
    size_t off = 0;
    auto alloc = [&](size_t bytes) -> void* {
        off = (off + 255) & ~(size_t)255;
        void* p = ws + off;
        off += bytes;
        return p;
    };
    float* bias_comb = (float*)alloc(Hdim * 4);
    u16* WcombPack = (u16*)alloc(Hdim * Hdim * 2);
    u16* Ws1Pack = (u16*)alloc(Hdim * Hdim * 2);
    int* cursor = (int*)alloc(Pn * 4);
    int* entries = (int*)alloc((size_t)Pn * CAP * 4);       // 12.8 MB bucketed CSR
    u16* M = (u16*)alloc((size_t)NClause * Hdim * 2);       // 20.5 MB per-clause messages
    u16* msgs = (u16*)alloc((size_t)Pn * Hdim * 2);         // 12.8 MB

    // 1. fused setup: weight fold + both packs + bias + cursor zero
    setup_kernel<<<Hdim, Hdim, 0, stream>>>(W_vc, b_vc, W_ce, b_ce, W_cv, b_cv, W_s1,
                                            WcombPack, Ws1Pack, bias_comb, cursor);
    // 2. bucketed CSR
    fill_kernel<<<(NClause + 255) / 256, 256, 0, stream>>>(ci, cursor, entries);

    // 3-4. iter 1: M = W*mean3(vs0) + b per clause; msgs1 = masked mean over buckets
    clause_kernel<1><<<NClause / 128, 512, 0, stream>>>(ci, vs0, nullptr, WcombPack, bias_comb, M);
    var_kernel<<<(Pn + 3) / 4, 256, 0, stream>>>(M, cursor, entries, msgs, 0);
    // 5-6. iter 2: M2 = W*mean3(msgs1) per clause; msgs2 = 2*msgs1 + masked mean
    clause_kernel<0><<<NClause / 128, 512, 0, stream>>>(ci, nullptr, msgs, WcombPack, bias_comb, M);
    var_kernel<<<(Pn + 3) / 4, 256, 0, stream>>>(M, cursor, entries, msgs, 1);
    // 7. readout
    final_kernel<<<(NRows + 127) / 128, 512, 0, stream>>>(vs0, msgs, Ws1Pack, b_s1, W_s2, b_s2, out);
}

// Round 10
// 162.294 us; speedup vs baseline: 1.0838x; 1.0838x over previous
//
#include <hip/hip_runtime.h>
#include <math.h>

using u16 = unsigned short;
using u32 = unsigned int;

namespace {
constexpr int Hdim = 128;
constexpr int Pn = 50000;
constexpr int Cn = 20000;
constexpr int Bn = 4;
constexpr int NClause = Bn * Cn;   // 80000
constexpr int NRows = Bn * Pn;     // 200000
constexpr int CAP = 64;            // max clauses per variable (mean deg 4.8; P(>=64) ~ e^-150)
}

typedef __attribute__((ext_vector_type(4))) float f32x4;
typedef __attribute__((ext_vector_type(8))) short bf16x8;

static __device__ __forceinline__ float bf2f(u16 v) {
    u32 u = ((u32)v) << 16;
    return __builtin_bit_cast(float, u);
}
static __device__ __forceinline__ u16 f2bf(float f) {
    u32 u = __builtin_bit_cast(u32, f);
    u32 r = u + 0x7FFFu + ((u >> 16) & 1u);
    return (u16)(r >> 16);
}

// ONE setup kernel: redundant per-row weight-chain (no inter-stage sync), packs
// Wcomb & W_s1 into MFMA B-frag layout, folds bias, zeros cursor.
__global__ __launch_bounds__(128) void setup_kernel(
    const float* __restrict__ W_vc, const float* __restrict__ b_vc,
    const float* __restrict__ W_ce, const float* __restrict__ b_ce,
    const float* __restrict__ W_cv, const float* __restrict__ b_cv,
    const float* __restrict__ W_s1,
    u16* __restrict__ WcombPack, u16* __restrict__ Ws1Pack,
    float* __restrict__ bias_comb, int* __restrict__ cursor) {
    int o = blockIdx.x, t = threadIdx.x;
    __shared__ float u[Hdim];
    __shared__ float red[Hdim];
    float acc = 0.f;
#pragma unroll 8
    for (int h = 0; h < Hdim; ++h) acc = fmaf(W_cv[o * Hdim + h], W_ce[h * Hdim + t], acc);
    u[t] = acc;
    float b1 = b_ce[t];
#pragma unroll 8
    for (int h = 0; h < Hdim; ++h) b1 = fmaf(W_ce[t * Hdim + h], b_vc[h], b1);
    red[t] = W_cv[o * Hdim + t] * b1;
    __syncthreads();
#pragma unroll
    for (int s = 64; s > 0; s >>= 1) {
        if (t < s) red[t] += red[t + s];
        __syncthreads();
    }
    if (t == 0) bias_comb[o] = red[0] + b_cv[o];
    float w = 0.f;
#pragma unroll 8
    for (int h = 0; h < Hdim; ++h) w = fmaf(u[h], W_vc[h * Hdim + t], w);
    // pack element (n=o, k=t): dst[((nt*4+ks)*64 + lane)*8 + j], lane = lofs*16 + (n&15)
    int nt = o >> 4, ks = t >> 5, lofs = (t >> 3) & 3, j = t & 7;
    int lane = lofs * 16 + (o & 15);
    size_t dst = (size_t)(((nt * 4 + ks) * 64 + lane)) * 8 + j;
    WcombPack[dst] = f2bf(w);
    Ws1Pack[dst] = f2bf(W_s1[o * Hdim + t]);
    for (int i = o * 128 + t; i < Pn; i += 128 * 128) cursor[i] = 0;
}

// bucketed CSR: entries[p*CAP + pos] = fid, cursor[p] = degree (first-occurrence dedup)
__global__ void fill_kernel(const int* __restrict__ ci, int* __restrict__ cursor,
                            int* __restrict__ entries) {
    int fid = blockIdx.x * blockDim.x + threadIdx.x;
    if (fid >= NClause) return;
    int i0 = ci[fid * 3 + 0], i1 = ci[fid * 3 + 1], i2 = ci[fid * 3 + 2];
    int pos = atomicAdd(&cursor[i0], 1);
    entries[i0 * CAP + pos] = fid;
    if (i1 != i0) { pos = atomicAdd(&cursor[i1], 1); entries[i1 * CAP + pos] = fid; }
    if (i2 != i0 && i2 != i1) { pos = atomicAdd(&cursor[i2], 1); entries[i2 * CAP + pos] = fid; }
}

// Fused gather + mean + GEMM per clause (128-row tile, 512 thr, LDS-staged A,
// Atile reused as output staging): M[fid] = bf16(W*mean3(rows) + (FROM_F32?bias:0))
template <int FROM_F32>
__global__ __launch_bounds__(512) void clause_kernel(
    const int* __restrict__ ci, const float* __restrict__ vs0, const u16* __restrict__ msgs,
    const u16* __restrict__ Bpack, const float* __restrict__ bias, u16* __restrict__ M) {
    __shared__ __align__(16) u16 Atile[128 * 136];   // 34.8 KB (input, then output)
    __shared__ __align__(16) u16 Btile[128 * 128];   // 32 KB
    int tid = threadIdx.x;
    int block0 = blockIdx.x * 128;
    {   // stage packed B
        const bf16x8* s = (const bf16x8*)Bpack;
        bf16x8* d = (bf16x8*)Btile;
#pragma unroll
        for (int i = 0; i < 4; ++i) d[tid + i * 512] = s[tid + i * 512];
    }
    // cooperative coalesced gather: 16 threads stream each row
#pragma unroll
    for (int pass = 0; pass < 4; ++pass) {
        int t = pass * 512 + tid;
        int r = t >> 4, seg = t & 15;
        int fid = block0 + r;
        int i0 = ci[fid * 3 + 0], i1 = ci[fid * 3 + 1], i2 = ci[fid * 3 + 2];
        int co = seg * 8;
        float s[8];
        if (FROM_F32) {
            const float* base = vs0 + (size_t)(fid / Cn) * Pn * Hdim;
            const float* r0 = base + (size_t)i0 * Hdim + co;
            const float* r1 = base + (size_t)i1 * Hdim + co;
            const float* r2 = base + (size_t)i2 * Hdim + co;
            f32x4 a0 = *(const f32x4*)r0, a1 = *(const f32x4*)(r0 + 4);
            f32x4 b0 = *(const f32x4*)r1, b1 = *(const f32x4*)(r1 + 4);
            f32x4 c0 = *(const f32x4*)r2, c1 = *(const f32x4*)(r2 + 4);
#pragma unroll
            for (int j = 0; j < 4; ++j) {
                s[j] = a0[j] + b0[j] + c0[j];
                s[j + 4] = a1[j] + b1[j] + c1[j];
            }
        } else {
            bf16x8 v0 = *(const bf16x8*)(msgs + (size_t)i0 * Hdim + co);
            bf16x8 v1 = *(const bf16x8*)(msgs + (size_t)i1 * Hdim + co);
            bf16x8 v2 = *(const bf16x8*)(msgs + (size_t)i2 * Hdim + co);
#pragma unroll
            for (int j = 0; j < 8; ++j)
                s[j] = bf2f((u16)v0[j]) + bf2f((u16)v1[j]) + bf2f((u16)v2[j]);
        }
        bf16x8 o;
#pragma unroll
        for (int j = 0; j < 8; ++j) o[j] = (short)f2bf(s[j] * (1.f / 3.f));
        *(bf16x8*)(&Atile[r * 136 + seg * 8]) = o;
    }
    __syncthreads();
    int w = tid >> 6, l = tid & 63;
    int arow = w * 16 + (l & 15);
    int kofs = (l >> 4) * 8;
    f32x4 acc[8];
#pragma unroll
    for (int nt = 0; nt < 8; ++nt) acc[nt] = (f32x4){0.f, 0.f, 0.f, 0.f};
#pragma unroll
    for (int ks = 0; ks < 4; ++ks) {
        bf16x8 af = *(const bf16x8*)(&Atile[arow * 136 + ks * 32 + kofs]);
#pragma unroll
        for (int nt = 0; nt < 8; ++nt) {
            bf16x8 bfr = *(const bf16x8*)(&Btile[((nt * 4 + ks) * 64 + l) * 8]);
            acc[nt] = __builtin_amdgcn_mfma_f32_16x16x32_bf16(af, bfr, acc[nt], 0, 0, 0);
        }
    }
    __syncthreads();   // all A-reads done; reuse Atile for output staging
    int crow = w * 16 + (l >> 4) * 4;
#pragma unroll
    for (int nt = 0; nt < 8; ++nt) {
        int col = nt * 16 + (l & 15);
        float bc = FROM_F32 ? bias[col] : 0.f;   // iter2: bias algebraically absorbed
#pragma unroll
        for (int reg = 0; reg < 4; ++reg)
            Atile[(crow + reg) * 136 + col] = f2bf(acc[nt][reg] + bc);
    }
    __syncthreads();
#pragma unroll
    for (int pass = 0; pass < 4; ++pass) {
        int t = pass * 512 + tid;
        int r = t >> 4, seg = t & 15;
        *(bf16x8*)(M + (size_t)(block0 + r) * Hdim + seg * 8) =
            *(const bf16x8*)(&Atile[r * 136 + seg * 8]);
    }
}

// iter1: msgs[p] = deg>0 ? (1/deg) sum M[fid] : 0          (= mask(W*V1 + b))
// iter2: msgs[p] = 2*msgs[p] + (deg>0 ? (1/deg) sum M[fid] : 0)
// 1 wave per variable: gathers need TLP.
__global__ __launch_bounds__(256) void var_kernel(const u16* __restrict__ M,
                                                  const int* __restrict__ counts,
                                                  const int* __restrict__ entries,
                                                  u16* __restrict__ msgs, int iter2) {
    int wave = threadIdx.x >> 6, lane = threadIdx.x & 63;
    int p = blockIdx.x * 4 + wave;
    if (p >= Pn) return;
    int deg = counts[p];
    const int* ep = entries + p * CAP;
    float a0 = 0.f, a1 = 0.f;
    for (int e = 0; e < deg; ++e) {
        int cid = ep[e];
        u32 v = *(const u32*)(M + (size_t)cid * Hdim + lane * 2);
        a0 += bf2f((u16)(v & 0xffffu));
        a1 += bf2f((u16)(v >> 16));
    }
    if (deg > 0) { float inv = 1.f / (float)deg; a0 *= inv; a1 *= inv; }
    u32* mp = (u32*)(msgs + (size_t)p * Hdim + lane * 2);
    if (iter2) {
        u32 old = *mp;
        a0 += 2.f * bf2f((u16)(old & 0xffffu));
        a1 += 2.f * bf2f((u16)(old >> 16));
    }
    *mp = (u32)f2bf(a0) | ((u32)f2bf(a1) << 16);
}

// out[row] = sigmoid( W_s2 . relu( (vs0[row]+msgs[row%Pn]) * W_s1^T + b_s1 ) + b_s2 )
// 128-row tile, 512 thr, LDS-staged A (coalesced stream).
__global__ __launch_bounds__(512) void final_kernel(
    const float* __restrict__ vs0, const u16* __restrict__ msgs, const u16* __restrict__ Bpack,
    const float* __restrict__ b_s1, const float* __restrict__ W_s2, const float* __restrict__ b_s2,
    float* __restrict__ out) {
    __shared__ __align__(16) u16 Atile[128 * 136];
    __shared__ __align__(16) u16 Btile[128 * 128];
    int tid = threadIdx.x;
    int block0 = blockIdx.x * 128;
    {
        const bf16x8* s = (const bf16x8*)Bpack;
        bf16x8* d = (bf16x8*)Btile;
#pragma unroll
        for (int i = 0; i < 4; ++i) d[tid + i * 512] = s[tid + i * 512];
    }
#pragma unroll
    for (int pass = 0; pass < 4; ++pass) {
        int t = pass * 512 + tid;
        int r = t >> 4, seg = t & 15;
        int row = block0 + r;
        int rowc = row < NRows ? row : NRows - 1;
        int p = rowc % Pn;
        int co = seg * 8;
        const float* vp = vs0 + (size_t)rowc * Hdim + co;
        f32x4 x = *(const f32x4*)vp, y = *(const f32x4*)(vp + 4);
        bf16x8 m = *(const bf16x8*)(msgs + (size_t)p * Hdim + co);
        bf16x8 o;
#pragma unroll
        for (int j = 0; j < 4; ++j) {
            o[j] = (short)f2bf(x[j] + bf2f((u16)m[j]));
            o[j + 4] = (short)f2bf(y[j] + bf2f((u16)m[j + 4]));
        }
        *(bf16x8*)(&Atile[r * 136 + seg * 8]) = o;
    }
    __syncthreads();
    int w = tid >> 6, l = tid & 63;
    int arow = w * 16 + (l & 15);
    int kofs = (l >> 4) * 8;
    f32x4 acc[8];
#pragma unroll
    for (int nt = 0; nt < 8; ++nt) acc[nt] = (f32x4){0.f, 0.f, 0.f, 0.f};
#pragma unroll
    for (int ks = 0; ks < 4; ++ks) {
        bf16x8 af = *(const bf16x8*)(&Atile[arow * 136 + ks * 32 + kofs]);
#pragma unroll
        for (int nt = 0; nt < 8; ++nt) {
            bf16x8 bfr = *(const bf16x8*)(&Btile[((nt * 4 + ks) * 64 + l) * 8]);
            acc[nt] = __builtin_amdgcn_mfma_f32_16x16x32_bf16(af, bfr, acc[nt], 0, 0, 0);
        }
    }
    float part[4] = {0.f, 0.f, 0.f, 0.f};
#pragma unroll
    for (int nt = 0; nt < 8; ++nt) {
        int col = nt * 16 + (l & 15);
        float b1 = b_s1[col], w2 = W_s2[col];
#pragma unroll
        for (int reg = 0; reg < 4; ++reg)
            part[reg] += fmaxf(acc[nt][reg] + b1, 0.f) * w2;
    }
#pragma unroll
    for (int m = 1; m < 16; m <<= 1)
#pragma unroll
        for (int reg = 0; reg < 4; ++reg) part[reg] += __shfl_xor(part[reg], m, 64);
    if ((l & 15) == 0) {
        float lb = b_s2[0];
        int row0 = block0 + w * 16 + (l >> 4) * 4;
#pragma unroll
        for (int reg = 0; reg < 4; ++reg)
            if (row0 + reg < NRows)
                out[row0 + reg] = 1.f / (1.f + expf(-(part[reg] + lb)));
    }
}

extern "C" void kernel_launch(void* const* d_in, const int* in_sizes, int n_in,
                              void* d_out, int out_size, void* d_ws, size_t ws_size,
                              hipStream_t stream) {
    (void)in_sizes; (void)n_in; (void)out_size; (void)ws_size;
    const int* ci = (const int*)d_in[0];
    const float* vs0 = (const float*)d_in[1];
    const float* W_vc = (const float*)d_in[2];
    const float* b_vc = (const float*)d_in[3];
    const float* W_ce = (const float*)d_in[4];
    const float* b_ce = (const float*)d_in[5];
    const float* W_cv = (const float*)d_in[6];
    const float* b_cv = (const float*)d_in[7];
    const float* W_s1 = (const float*)d_in[8];
    const float* b_s1 = (const float*)d_in[9];
    const float* W_s2 = (const float*)d_in[10];
    const float* b_s2 = (const float*)d_in[11];
    float* out = (float*)d_out;

    char* ws = (char*)d_ws;
    size_t off = 0;
    auto alloc = [&](size_t bytes) -> void* {
        off = (off + 255) & ~(size_t)255;
        void* p = ws + off;
        off += bytes;
        return p;
    };
    float* bias_comb = (float*)alloc(Hdim * 4);
    u16* WcombPack = (u16*)alloc(Hdim * Hdim * 2);
    u16* Ws1Pack = (u16*)alloc(Hdim * Hdim * 2);
    int* cursor = (int*)alloc(Pn * 4);
    int* entries = (int*)alloc((size_t)Pn * CAP * 4);       // 12.8 MB bucketed CSR
    u16* M = (u16*)alloc((size_t)NClause * Hdim * 2);       // 20.5 MB per-clause messages
    u16* msgs = (u16*)alloc((size_t)Pn * Hdim * 2);         // 12.8 MB

    // 1. fused setup: weight fold + both packs + bias + cursor zero
    setup_kernel<<<Hdim, Hdim, 0, stream>>>(W_vc, b_vc, W_ce, b_ce, W_cv, b_cv, W_s1,
                                            WcombPack, Ws1Pack, bias_comb, cursor);
    // 2. bucketed CSR
    fill_kernel<<<(NClause + 255) / 256, 256, 0, stream>>>(ci, cursor, entries);

    // 3-4. iter 1: M = W*mean3(vs0) + b per clause; msgs1 = masked mean over buckets
    clause_kernel<1><<<NClause / 128, 512, 0, stream>>>(ci, vs0, nullptr, WcombPack, bias_comb, M);
    var_kernel<<<(Pn + 3) / 4, 256, 0, stream>>>(M, cursor, entries, msgs, 0);
    // 5-6. iter 2: M2 = W*mean3(msgs1) per clause; msgs2 = 2*msgs1 + masked mean
    clause_kernel<0><<<NClause / 128, 512, 0, stream>>>(ci, nullptr, msgs, WcombPack, bias_comb, M);
    var_kernel<<<(Pn + 3) / 4, 256, 0, stream>>>(M, cursor, entries, msgs, 1);
    // 7. readout
    final_kernel<<<(NRows + 127) / 128, 512, 0, stream>>>(vs0, msgs, Ws1Pack, b_s1, W_s2, b_s2, out);
}

// Round 11
// 135.446 us; speedup vs baseline: 1.2987x; 1.1982x over previous
//
#include <hip/hip_runtime.h>
#include <math.h>

using u16 = unsigned short;
using u32 = unsigned int;

namespace {
constexpr int Hdim = 128;
constexpr int Pn = 50000;
constexpr int Cn = 20000;
constexpr int Bn = 4;
constexpr int NClause = Bn * Cn;   // 80000
constexpr int NRows = Bn * Pn;     // 200000
constexpr int CAP = 64;            // max clauses per variable (mean deg 4.8; P(>=64) ~ e^-150)
}

typedef __attribute__((ext_vector_type(4))) float f32x4;
typedef __attribute__((ext_vector_type(8))) short bf16x8;

static __device__ __forceinline__ float bf2f(u16 v) {
    u32 u = ((u32)v) << 16;
    return __builtin_bit_cast(float, u);
}
static __device__ __forceinline__ u16 f2bf(float f) {
    u32 u = __builtin_bit_cast(u32, f);
    u32 r = u + 0x7FFFu + ((u >> 16) & 1u);
    return (u16)(r >> 16);
}

// ONE setup kernel: redundant per-row weight-chain (no inter-stage sync), packs
// Wcomb & W_s1 into MFMA B-frag layout, folds bias, zeros cursor.
__global__ __launch_bounds__(128) void setup_kernel(
    const float* __restrict__ W_vc, const float* __restrict__ b_vc,
    const float* __restrict__ W_ce, const float* __restrict__ b_ce,
    const float* __restrict__ W_cv, const float* __restrict__ b_cv,
    const float* __restrict__ W_s1,
    u16* __restrict__ WcombPack, u16* __restrict__ Ws1Pack,
    float* __restrict__ bias_comb, int* __restrict__ cursor) {
    int o = blockIdx.x, t = threadIdx.x;
    __shared__ float u[Hdim];
    __shared__ float red[Hdim];
    float acc = 0.f;
#pragma unroll 8
    for (int h = 0; h < Hdim; ++h) acc = fmaf(W_cv[o * Hdim + h], W_ce[h * Hdim + t], acc);
    u[t] = acc;
    float b1 = b_ce[t];
#pragma unroll 8
    for (int h = 0; h < Hdim; ++h) b1 = fmaf(W_ce[t * Hdim + h], b_vc[h], b1);
    red[t] = W_cv[o * Hdim + t] * b1;
    __syncthreads();
#pragma unroll
    for (int s = 64; s > 0; s >>= 1) {
        if (t < s) red[t] += red[t + s];
        __syncthreads();
    }
    if (t == 0) bias_comb[o] = red[0] + b_cv[o];
    float w = 0.f;
#pragma unroll 8
    for (int h = 0; h < Hdim; ++h) w = fmaf(u[h], W_vc[h * Hdim + t], w);
    // pack element (n=o, k=t): dst[((nt*4+ks)*64 + lane)*8 + j], lane = lofs*16 + (n&15)
    int nt = o >> 4, ks = t >> 5, lofs = (t >> 3) & 3, j = t & 7;
    int lane = lofs * 16 + (o & 15);
    size_t dst = (size_t)(((nt * 4 + ks) * 64 + lane)) * 8 + j;
    WcombPack[dst] = f2bf(w);
    Ws1Pack[dst] = f2bf(W_s1[o * Hdim + t]);
    for (int i = o * 128 + t; i < Pn; i += 128 * 128) cursor[i] = 0;
}

// Fused (optional CSR-fill) + gather + mean + GEMM per clause (64-row tile, 256 thr):
//   M[fid] = bf16( W * mean3(rows) + (FROM_F32 ? bias : 0) )
// DO_FILL: this block also writes the bucketed CSR for its 64 clauses; the
// atomics' latency hides under the gather, and the CSR is complete at kernel
// end — exactly when var_kernel needs it.
template <int FROM_F32, int DO_FILL>
__global__ __launch_bounds__(256) void clause_kernel(
    const int* __restrict__ ci, const float* __restrict__ vs0, const u16* __restrict__ msgs,
    const u16* __restrict__ Bpack, const float* __restrict__ bias, u16* __restrict__ M,
    int* __restrict__ cursor, int* __restrict__ entries) {
    __shared__ __align__(16) u16 Atile[64 * 136];   // 272B row pitch (input, then output)
    __shared__ __align__(16) u16 Btile[128 * 128];
    int tid = threadIdx.x;
    int block0 = blockIdx.x * 64;
    {   // stage packed B (32KB)
        const bf16x8* s = (const bf16x8*)Bpack;
        bf16x8* d = (bf16x8*)Btile;
#pragma unroll
        for (int i = 0; i < 8; ++i) d[tid + i * 256] = s[tid + i * 256];
    }
    if (DO_FILL && tid < 64) {
        int fid = block0 + tid;
        int i0 = ci[fid * 3 + 0], i1 = ci[fid * 3 + 1], i2 = ci[fid * 3 + 2];
        int pos = atomicAdd(&cursor[i0], 1);
        entries[i0 * CAP + pos] = fid;
        if (i1 != i0) { pos = atomicAdd(&cursor[i1], 1); entries[i1 * CAP + pos] = fid; }
        if (i2 != i0 && i2 != i1) { pos = atomicAdd(&cursor[i2], 1); entries[i2 * CAP + pos] = fid; }
    }
    // cooperative coalesced gather: 16 threads stream each row
#pragma unroll
    for (int pass = 0; pass < 4; ++pass) {
        int t = pass * 256 + tid;
        int r = t >> 4, seg = t & 15;
        int fid = block0 + r;
        int i0 = ci[fid * 3 + 0], i1 = ci[fid * 3 + 1], i2 = ci[fid * 3 + 2];
        int co = seg * 8;
        float s[8];
        if (FROM_F32) {
            const float* base = vs0 + (size_t)(fid / Cn) * Pn * Hdim;
            const float* r0 = base + (size_t)i0 * Hdim + co;
            const float* r1 = base + (size_t)i1 * Hdim + co;
            const float* r2 = base + (size_t)i2 * Hdim + co;
            f32x4 a0 = *(const f32x4*)r0, a1 = *(const f32x4*)(r0 + 4);
            f32x4 b0 = *(const f32x4*)r1, b1 = *(const f32x4*)(r1 + 4);
            f32x4 c0 = *(const f32x4*)r2, c1 = *(const f32x4*)(r2 + 4);
#pragma unroll
            for (int j = 0; j < 4; ++j) {
                s[j] = a0[j] + b0[j] + c0[j];
                s[j + 4] = a1[j] + b1[j] + c1[j];
            }
        } else {
            bf16x8 v0 = *(const bf16x8*)(msgs + (size_t)i0 * Hdim + co);
            bf16x8 v1 = *(const bf16x8*)(msgs + (size_t)i1 * Hdim + co);
            bf16x8 v2 = *(const bf16x8*)(msgs + (size_t)i2 * Hdim + co);
#pragma unroll
            for (int j = 0; j < 8; ++j)
                s[j] = bf2f((u16)v0[j]) + bf2f((u16)v1[j]) + bf2f((u16)v2[j]);
        }
        bf16x8 o;
#pragma unroll
        for (int j = 0; j < 8; ++j) o[j] = (short)f2bf(s[j] * (1.f / 3.f));
        *(bf16x8*)(&Atile[r * 136 + seg * 8]) = o;
    }
    __syncthreads();
    int w = tid >> 6, l = tid & 63;
    int arow = w * 16 + (l & 15);
    int kofs = (l >> 4) * 8;
    f32x4 acc[8];
#pragma unroll
    for (int nt = 0; nt < 8; ++nt) acc[nt] = (f32x4){0.f, 0.f, 0.f, 0.f};
#pragma unroll
    for (int ks = 0; ks < 4; ++ks) {
        bf16x8 af = *(const bf16x8*)(&Atile[arow * 136 + ks * 32 + kofs]);
#pragma unroll
        for (int nt = 0; nt < 8; ++nt) {
            bf16x8 bfr = *(const bf16x8*)(&Btile[((nt * 4 + ks) * 64 + l) * 8]);
            acc[nt] = __builtin_amdgcn_mfma_f32_16x16x32_bf16(af, bfr, acc[nt], 0, 0, 0);
        }
    }
    __syncthreads();   // all A-reads done; reuse Atile for output staging
    int crow = w * 16 + (l >> 4) * 4;
#pragma unroll
    for (int nt = 0; nt < 8; ++nt) {
        int col = nt * 16 + (l & 15);
        float bc = FROM_F32 ? bias[col] : 0.f;   // iter2: bias algebraically absorbed
#pragma unroll
        for (int reg = 0; reg < 4; ++reg)
            Atile[(crow + reg) * 136 + col] = f2bf(acc[nt][reg] + bc);
    }
    __syncthreads();
#pragma unroll
    for (int pass = 0; pass < 4; ++pass) {
        int t = pass * 256 + tid;
        int r = t >> 4, seg = t & 15;
        *(bf16x8*)(M + (size_t)(block0 + r) * Hdim + seg * 8) =
            *(const bf16x8*)(&Atile[r * 136 + seg * 8]);
    }
}

// iter1: msgs[p] = deg>0 ? (1/deg) sum M[fid] : 0          (= mask(W*V1 + b))
// iter2: msgs[p] = 2*msgs[p] + (deg>0 ? (1/deg) sum M[fid] : 0)
// 1 wave per variable; entries loop unrolled x2 with dual accumulators for MLP.
__global__ __launch_bounds__(256) void var_kernel(const u16* __restrict__ M,
                                                  const int* __restrict__ counts,
                                                  const int* __restrict__ entries,
                                                  u16* __restrict__ msgs, int iter2) {
    int wave = threadIdx.x >> 6, lane = threadIdx.x & 63;
    int p = blockIdx.x * 4 + wave;
    if (p >= Pn) return;
    int deg = counts[p];
    const int* ep = entries + p * CAP;
    float a0 = 0.f, a1 = 0.f, c0 = 0.f, c1 = 0.f;
    int e = 0;
    for (; e + 1 < deg; e += 2) {
        int cidA = ep[e], cidB = ep[e + 1];
        u32 vA = *(const u32*)(M + (size_t)cidA * Hdim + lane * 2);
        u32 vB = *(const u32*)(M + (size_t)cidB * Hdim + lane * 2);
        a0 += bf2f((u16)(vA & 0xffffu));
        a1 += bf2f((u16)(vA >> 16));
        c0 += bf2f((u16)(vB & 0xffffu));
        c1 += bf2f((u16)(vB >> 16));
    }
    if (e < deg) {
        u32 v = *(const u32*)(M + (size_t)ep[e] * Hdim + lane * 2);
        a0 += bf2f((u16)(v & 0xffffu));
        a1 += bf2f((u16)(v >> 16));
    }
    a0 += c0; a1 += c1;
    if (deg > 0) { float inv = 1.f / (float)deg; a0 *= inv; a1 *= inv; }
    u32* mp = (u32*)(msgs + (size_t)p * Hdim + lane * 2);
    if (iter2) {
        u32 old = *mp;
        a0 += 2.f * bf2f((u16)(old & 0xffffu));
        a1 += 2.f * bf2f((u16)(old >> 16));
    }
    *mp = (u32)f2bf(a0) | ((u32)f2bf(a1) << 16);
}

// out[row] = sigmoid( W_s2 . relu( (vs0[row]+msgs[row%Pn]) * W_s1^T + b_s1 ) + b_s2 )
// Persistent grid-stride: Btile staged ONCE per block, blocks sweep 64-row tiles.
__global__ __launch_bounds__(256) void final_kernel(
    const float* __restrict__ vs0, const u16* __restrict__ msgs, const u16* __restrict__ Bpack,
    const float* __restrict__ b_s1, const float* __restrict__ W_s2, const float* __restrict__ b_s2,
    float* __restrict__ out, int ntiles) {
    __shared__ __align__(16) u16 Atile[64 * 136];
    __shared__ __align__(16) u16 Btile[128 * 128];
    int tid = threadIdx.x;
    {
        const bf16x8* s = (const bf16x8*)Bpack;
        bf16x8* d = (bf16x8*)Btile;
#pragma unroll
        for (int i = 0; i < 8; ++i) d[tid + i * 256] = s[tid + i * 256];
    }
    int w = tid >> 6, l = tid & 63;
    int arow = w * 16 + (l & 15);
    int kofs = (l >> 4) * 8;
    for (int tile = blockIdx.x; tile < ntiles; tile += gridDim.x) {
        __syncthreads();   // Btile ready (1st iter) / prev MFMA A-reads done (later iters)
        int block0 = tile * 64;
#pragma unroll
        for (int pass = 0; pass < 4; ++pass) {
            int t = pass * 256 + tid;
            int r = t >> 4, seg = t & 15;
            int row = block0 + r;
            int p = row % Pn;
            int co = seg * 8;
            const float* vp = vs0 + (size_t)row * Hdim + co;
            f32x4 x = *(const f32x4*)vp, y = *(const f32x4*)(vp + 4);
            bf16x8 m = *(const bf16x8*)(msgs + (size_t)p * Hdim + co);
            bf16x8 o;
#pragma unroll
            for (int j = 0; j < 4; ++j) {
                o[j] = (short)f2bf(x[j] + bf2f((u16)m[j]));
                o[j + 4] = (short)f2bf(y[j] + bf2f((u16)m[j + 4]));
            }
            *(bf16x8*)(&Atile[r * 136 + seg * 8]) = o;
        }
        __syncthreads();
        f32x4 acc[8];
#pragma unroll
        for (int nt = 0; nt < 8; ++nt) acc[nt] = (f32x4){0.f, 0.f, 0.f, 0.f};
#pragma unroll
        for (int ks = 0; ks < 4; ++ks) {
            bf16x8 af = *(const bf16x8*)(&Atile[arow * 136 + ks * 32 + kofs]);
#pragma unroll
            for (int nt = 0; nt < 8; ++nt) {
                bf16x8 bfr = *(const bf16x8*)(&Btile[((nt * 4 + ks) * 64 + l) * 8]);
                acc[nt] = __builtin_amdgcn_mfma_f32_16x16x32_bf16(af, bfr, acc[nt], 0, 0, 0);
            }
        }
        float part[4] = {0.f, 0.f, 0.f, 0.f};
#pragma unroll
        for (int nt = 0; nt < 8; ++nt) {
            int col = nt * 16 + (l & 15);
            float b1 = b_s1[col], w2 = W_s2[col];
#pragma unroll
            for (int reg = 0; reg < 4; ++reg)
                part[reg] += fmaxf(acc[nt][reg] + b1, 0.f) * w2;
        }
#pragma unroll
        for (int m = 1; m < 16; m <<= 1)
#pragma unroll
            for (int reg = 0; reg < 4; ++reg) part[reg] += __shfl_xor(part[reg], m, 64);
        if ((l & 15) == 0) {
            float lb = b_s2[0];
            int row0 = block0 + w * 16 + (l >> 4) * 4;
#pragma unroll
            for (int reg = 0; reg < 4; ++reg)
                out[row0 + reg] = 1.f / (1.f + expf(-(part[reg] + lb)));
        }
    }
}

extern "C" void kernel_launch(void* const* d_in, const int* in_sizes, int n_in,
                              void* d_out, int out_size, void* d_ws, size_t ws_size,
                              hipStream_t stream) {
    (void)in_sizes; (void)n_in; (void)out_size; (void)ws_size;
    const int* ci = (const int*)d_in[0];
    const float* vs0 = (const float*)d_in[1];
    const float* W_vc = (const float*)d_in[2];
    const float* b_vc = (const float*)d_in[3];
    const float* W_ce = (const float*)d_in[4];
    const float* b_ce = (const float*)d_in[5];
    const float* W_cv = (const float*)d_in[6];
    const float* b_cv = (const float*)d_in[7];
    const float* W_s1 = (const float*)d_in[8];
    const float* b_s1 = (const float*)d_in[9];
    const float* W_s2 = (const float*)d_in[10];
    const float* b_s2 = (const float*)d_in[11];
    float* out = (float*)d_out;

    char* ws = (char*)d_ws;
    size_t off = 0;
    auto alloc = [&](size_t bytes) -> void* {
        off = (off + 255) & ~(size_t)255;
        void* p = ws + off;
        off += bytes;
        return p;
    };
    float* bias_comb = (float*)alloc(Hdim * 4);
    u16* WcombPack = (u16*)alloc(Hdim * Hdim * 2);
    u16* Ws1Pack = (u16*)alloc(Hdim * Hdim * 2);
    int* cursor = (int*)alloc(Pn * 4);
    int* entries = (int*)alloc((size_t)Pn * CAP * 4);       // 12.8 MB bucketed CSR
    u16* M = (u16*)alloc((size_t)NClause * Hdim * 2);       // 20.5 MB per-clause messages
    u16* msgs = (u16*)alloc((size_t)Pn * Hdim * 2);         // 12.8 MB

    // 1. fused setup: weight fold + both packs + bias + cursor zero
    setup_kernel<<<Hdim, Hdim, 0, stream>>>(W_vc, b_vc, W_ce, b_ce, W_cv, b_cv, W_s1,
                                            WcombPack, Ws1Pack, bias_comb, cursor);
    // 2-3. iter 1: clause1 also builds the CSR (complete by kernel end, before var1)
    clause_kernel<1, 1><<<NClause / 64, 256, 0, stream>>>(ci, vs0, nullptr, WcombPack,
                                                          bias_comb, M, cursor, entries);
    var_kernel<<<(Pn + 3) / 4, 256, 0, stream>>>(M, cursor, entries, msgs, 0);
    // 4-5. iter 2: M2 = W*mean3(msgs1) per clause; msgs2 = 2*msgs1 + masked mean
    clause_kernel<0, 0><<<NClause / 64, 256, 0, stream>>>(ci, nullptr, msgs, WcombPack,
                                                          bias_comb, M, cursor, entries);
    var_kernel<<<(Pn + 3) / 4, 256, 0, stream>>>(M, cursor, entries, msgs, 1);
    // 6. readout (persistent: 3 blocks/CU x 256 CUs)
    final_kernel<<<768, 256, 0, stream>>>(vs0, msgs, Ws1Pack, b_s1, W_s2, b_s2, out,
                                          NRows / 64);
}